// Round 14
// baseline (3264.515 us; speedup 1.0000x reference)
//
#include <hip/hip_runtime.h>

typedef unsigned short u16;
typedef unsigned int   u32;
typedef u16 bfx8 __attribute__((ext_vector_type(8)));
typedef __bf16 bf16x8 __attribute__((ext_vector_type(8)));
typedef float  f32x4  __attribute__((ext_vector_type(4)));

#define NH  128          // hidden dim H
#define NF  384          // feature dim F = 3H
#define K2F 768          // 2F
#define NG4 1536         // 4F

__device__ __forceinline__ float bf2f(u16 u){ return __uint_as_float(((u32)u) << 16); }
__device__ __forceinline__ u16 f2bf(float f){
  __bf16 h = (__bf16)f;
  return __builtin_bit_cast(u16, h);
}
__device__ __forceinline__ float fsig(float x){ return 1.0f / (1.0f + __expf(-x)); }
__device__ __forceinline__ float ftanh(float x){ return 1.0f - 2.0f / (__expf(2.0f * x) + 1.0f); }

struct P {
  const int *unit_type, *n2g;
  const void *embed, *w1, *b1, *w2, *b2, *gwih, *gwhh, *gbih, *gbhh, *lwih, *lwhh, *lbih, *lbhh;
  int *flag, *segS, *segE;
  u16 *embedB;                           // bf16 embed table
  u16 *W1eb, *W2b, *Wihb, *Whhb;         // bf16 canonical weights (stage A)
  float *b1f, *b2f, *bihG, *bhhG;
  u16 *WcatB;                            // fused LSTM weight [1536][768] bf16
  float *bsum;                           // [1536]
  float *h1v, *c1v;                      // step-1 LSTM single row (broadcast)
  float *hbuf, *cbuf, *pooled;           // [B][384] f32
  u16 *xcatB;                            // [B][768] bf16
  float *gout;                           // [B][1536] f32
  u16 *nfb;                              // optional bf16 shadow of node_feature
  int useNfb;
  void *out; long qsz;
  int N, B, embedN;
};

__device__ __forceinline__ float ldin(const void* p, long i, int isbf){
  return isbf ? bf2f(((const u16*)p)[i]) : ((const float*)p)[i];
}

// ---------------- dtype detector ----------------
__global__ void k_detect(P p){
  __shared__ int cnt;
  if (threadIdx.x == 0) cnt = 0;
  __syncthreads();
  const u32* w = (const u32*)p.embed;
  const int nw = p.embedN / 2;
  int bad = 0;
  for (int i = threadIdx.x; i < nw; i += blockDim.x){
    u32 v = w[i];
    float fhi = __uint_as_float(v & 0xffff0000u);
    float flo = __uint_as_float(v << 16);
    if (!(fabsf(fhi) < 2.0f)) bad++;
    if (!(fabsf(flo) < 2.0f)) bad++;
  }
  atomicAdd(&cnt, bad);
  __syncthreads();
  if (threadIdx.x == 0) *p.flag = (cnt == 0) ? 1 : 0;
}

// ---------------- weight canonicalization ----------------
__global__ void k_prep(P p){
  long o = (long)blockIdx.x * 256 + threadIdx.x;
  const int isbf = *p.flag;
  if (o < p.embedN){ p.embedB[o] = f2bf(ldin(p.embed, o, isbf)); return; } o -= p.embedN;
  if (o < 16384){ long cc = o >> 7, k = o & 127;
    float v = ldin(p.w1, cc*256 + k, isbf) + ldin(p.w1, cc*256 + 128 + k, isbf);
    p.W1eb[o] = f2bf(v); return; } o -= 16384;
  if (o < 16384){ p.W2b[o]  = f2bf(ldin(p.w2, o, isbf));   return; } o -= 16384;
  if (o < 49152){ p.Wihb[o] = f2bf(ldin(p.gwih, o, isbf)); return; } o -= 49152;
  if (o < 49152){ p.Whhb[o] = f2bf(ldin(p.gwhh, o, isbf)); return; } o -= 49152;
  if (o < (long)NG4*K2F){ long j = o / K2F, k = o - j*K2F;
    float v = ldin(p.lwih, o, isbf);
    if (k < NF) v += ldin(p.lwhh, j*NF + k, isbf);
    p.WcatB[o] = f2bf(v); return; } o -= (long)NG4*K2F;
  if (o < NH){ p.b1f[o] = ldin(p.b1, o, isbf); return; } o -= NH;
  if (o < NH){ p.b2f[o] = ldin(p.b2, o, isbf); return; } o -= NH;
  if (o < NF){ p.bihG[o] = ldin(p.gbih, o, isbf); return; } o -= NF;
  if (o < NF){ p.bhhG[o] = ldin(p.gbhh, o, isbf); return; } o -= NF;
  if (o < NG4){ p.bsum[o] = ldin(p.lbih, o, isbf) + ldin(p.lbhh, o, isbf); return; } o -= NG4;
  if (o < p.B){ p.segS[o] = 0; p.segE[o] = 0; }
}

__global__ void k_segb(P p){
  int i = (int)blockIdx.x * 256 + threadIdx.x;
  if (i >= p.N) return;
  int g = p.n2g[i];
  if (g < 0 || g >= p.B) return;
  if (i == 0        || p.n2g[i-1] != g) p.segS[g] = i;
  if (i == p.N - 1  || p.n2g[i+1] != g) p.segE[g] = i + 1;
}

// ================= MFMA helpers =================
__device__ __forceinline__ f32x4 MF(bf16x8 a, bf16x8 b, f32x4 c){
  return __builtin_amdgcn_mfma_f32_16x16x32_bf16(a, b, c, 0, 0, 0);
}
__device__ __forceinline__ bf16x8 ldA(const u16* buf, int m0, int k0, int lane){
  const int row = m0 + (lane & 15);
  const int byte = (row*256 + (k0 + (lane>>4)*8)*2) ^ ((row&7)<<4);
  return *(const bf16x8*)((const char*)buf + byte);
}
__device__ __forceinline__ bf16x8 ldB(const u16* __restrict__ W, int n0, int k0, int lane){
  return *(const bf16x8*)(W + (long)(n0 + (lane&15))*NH + k0 + (lane>>4)*8);
}
__device__ __forceinline__ bf16x8 ldBs(const u16* __restrict__ W, long stride,
                                       int n0, int k0, int lane){
  return *(const bf16x8*)(W + (long)(n0 + (lane&15))*stride + k0 + (lane>>4)*8);
}
__device__ __forceinline__ void stLDS(u16* buf, int row, int col, float v){
  const int byte = (row*256 + col*2) ^ ((row&7)<<4);
  *(u16*)((char*)buf + byte) = f2bf(v);
}
__device__ __forceinline__ float ldLDS(const u16* buf, int row, int col){
  const int byte = (row*256 + col*2) ^ ((row&7)<<4);
  return bf2f(*(const u16*)((const char*)buf + byte));
}
__device__ __forceinline__ u16 ldLDSraw(const u16* buf, int row, int col){
  const int byte = (row*256 + col*2) ^ ((row&7)<<4);
  return *(const u16*)((const char*)buf + byte);
}

// ================= stage A (MFMA; BARRIER-FREE, wave-independent) =================
// 64 nodes/block, 4 waves; wave w owns rows w*16..w*16+15 exclusively.
// Each wave computes its 16 nodes end-to-end over ALL columns (weights
// re-read per wave from L2). Activations ping-pong between two 16-row
// LDS regions; all LDS deps are intra-wave (compiler waitcnts, no barriers).
__global__ __launch_bounds__(256, 3) void k_stageA_mfma(P p){
  __shared__ u16 bufA[64*128];
  __shared__ u16 bufB[64*128];
  const int t = (int)threadIdx.x;
  const int lane = t & 63, w = t >> 6;
  const int node0 = (int)blockIdx.x * 64;
  const int r0 = w * 16;                    // wave's private row base
  const int cL = lane & 15;
  const int isbf = *p.flag;

  u16* bufH = bufA;                         // h (layer input)
  u16* bufM = bufB;                         // m1 -> msg -> hnew

  { // gather embeddings into bufH rows r0..r0+15 (wave-local)
    const int row = r0 + (lane >> 2);
    const int seg = lane & 3;
    const int node = min(node0 + row, p.N - 1);
    int ut = p.unit_type[node];
    ut = min(max(ut, 0), p.embedN/NH - 1);
    const u16* src = p.embedB + (long)ut*NH + seg*32;
    #pragma unroll
    for (int i = 0; i < 4; ++i){
      const int col = seg*32 + i*8;
      const int byte = (row*256 + col*2) ^ ((row&7)<<4);
      *(bfx8*)((char*)bufH + byte) = *(const bfx8*)(src + i*8);
    }
  }

  u16*   out16 = (u16*)p.out;
  float* out32 = (float*)p.out;

  #pragma unroll 1
  for (int l = 0; l < 3; ++l){
    // A-fragments of h: complete 16x128 tile in 4 regs; live through P3
    bf16x8 ah[4];
    #pragma unroll
    for (int k = 0; k < 4; ++k) ah[k] = ldA(bufH, r0, k*32, lane);

    // ---- P1: m1 = relu(h @ W1e^T + b1) -> bufM
    #pragma unroll 1
    for (int ct = 0; ct < 8; ++ct){
      const float b = p.b1f[ct*16 + cL];
      f32x4 acc = {b,b,b,b};
      #pragma unroll
      for (int k = 0; k < 4; ++k){
        const bf16x8 bv = ldB(p.W1eb, ct*16, k*32, lane);
        acc = MF(ah[k], bv, acc);
      }
      #pragma unroll
      for (int j = 0; j < 4; ++j)
        stLDS(bufM, r0 + (lane>>4)*4 + j, ct*16 + cL, fmaxf(acc[j], 0.0f));
    }
    // ---- P2: msg = m1 @ W2^T + b2 -> bufM (m1 fully captured in am regs)
    {
      bf16x8 am[4];
      #pragma unroll
      for (int k = 0; k < 4; ++k) am[k] = ldA(bufM, r0, k*32, lane);
      #pragma unroll 1
      for (int ct = 0; ct < 8; ++ct){
        const float b = p.b2f[ct*16 + cL];
        f32x4 acc = {b,b,b,b};
        #pragma unroll
        for (int k = 0; k < 4; ++k){
          const bf16x8 bv = ldB(p.W2b, ct*16, k*32, lane);
          acc = MF(am[k], bv, acc);
        }
        #pragma unroll
        for (int j = 0; j < 4; ++j)
          stLDS(bufM, r0 + (lane>>4)*4 + j, ct*16 + cL, acc[j]);
      }
    }
    // ---- P3: per col-tile, all gates + GRU combine; hnew -> bufM
    {
      bf16x8 am[4];                         // msg (captured; bufM then reusable)
      #pragma unroll
      for (int k = 0; k < 4; ++k) am[k] = ldA(bufM, r0, k*32, lane);
      #pragma unroll 1
      for (int ct = 0; ct < 8; ++ct){
        const int c16 = ct*16 + cL;
        const float br = p.bihG[c16]       + p.bhhG[c16];
        const float bz = p.bihG[128 + c16] + p.bhhG[128 + c16];
        const float bi = p.bihG[256 + c16];
        const float bh = p.bhhG[256 + c16];
        f32x4 ar = {br,br,br,br}, az = {bz,bz,bz,bz};
        f32x4 ai = {bi,bi,bi,bi}, an = {bh,bh,bh,bh};
        #pragma unroll
        for (int k = 0; k < 4; ++k){
          bf16x8 bv;
          bv = ldB(p.Wihb,       ct*16, k*32, lane); ar = MF(am[k], bv, ar);
          bv = ldB(p.Whhb,       ct*16, k*32, lane); ar = MF(ah[k], bv, ar);
          bv = ldB(p.Wihb, 128 + ct*16, k*32, lane); az = MF(am[k], bv, az);
          bv = ldB(p.Whhb, 128 + ct*16, k*32, lane); az = MF(ah[k], bv, az);
          bv = ldB(p.Wihb, 256 + ct*16, k*32, lane); ai = MF(am[k], bv, ai);
          bv = ldB(p.Whhb, 256 + ct*16, k*32, lane); an = MF(ah[k], bv, an);
        }
        #pragma unroll
        for (int j = 0; j < 4; ++j){
          const int row = r0 + (lane>>4)*4 + j;
          const int col = ct*16 + cL;
          const float r = fsig(ar[j]);
          const float z = fsig(az[j]);
          const float nn = ftanh(fmaf(r, an[j], ai[j]));
          const float hv = ldLDS(bufH, row, col);
          stLDS(bufM, row, col, fmaf(z, hv - nn, nn));
        }
      }
    }
    // ---- Epilogue: wave writes its own 16 rows from bufM (dense stores)
    #pragma unroll 1
    for (int rj = 0; rj < 16; ++rj){
      const int row = r0 + rj;
      const int node = node0 + row;
      if (node < p.N){
        const u16 va = ldLDSraw(bufM, row, lane);
        const u16 vb = ldLDSraw(bufM, row, 64 + lane);
        const long fi = (long)node*NF + l*NH;
        if (isbf){
          __builtin_nontemporal_store(va, &out16[p.qsz + fi + lane]);
          __builtin_nontemporal_store(vb, &out16[p.qsz + fi + 64 + lane]);
        } else {
          __builtin_nontemporal_store(bf2f(va), &out32[p.qsz + fi + lane]);
          __builtin_nontemporal_store(bf2f(vb), &out32[p.qsz + fi + 64 + lane]);
          if (p.useNfb){
            __builtin_nontemporal_store(va, &p.nfb[fi + lane]);
            __builtin_nontemporal_store(vb, &p.nfb[fi + 64 + lane]);
          }
        }
      }
    }
    // swap: hnew becomes next layer's h
    u16* tmp = bufH; bufH = bufM; bufM = tmp;
  }
}

// ---------------- step-1 LSTM (inputs identically zero -> one row) ----------------
__global__ void k_lstm0(P p){
  const int d = (int)threadIdx.x;
  if (d >= NF) return;
  const float i_ = fsig(p.bsum[d]);
  const float gc = ftanh(p.bsum[2*NF + d]);
  const float o_ = fsig(p.bsum[3*NF + d]);
  const float cn = i_ * gc;                 // c0 = 0
  p.c1v[d] = cn;
  p.h1v[d] = o_ * ftanh(cn);
}

// ---------------- attention / Set2Set readout (one block per graph) ----------------
__global__ __launch_bounds__(256) void k_attn(P p, const float* __restrict__ qsrc,
                                              int qstride, int finalstep){
  __shared__ alignas(16) char raw[32 * NF * 4];     // 48 KB tile: bf16 or f32
  __shared__ float qs[NF];
  __shared__ float att[32];
  __shared__ float sM, sZ, sSc;

  u16*   nb = (u16*)raw;
  float* nfl = (float*)raw;
  const int t = (int)threadIdx.x;
  const int g = (int)blockIdx.x;
  const int isbf = *p.flag;
  const int bftile = isbf | p.useNfb;
  const u16* nbase = isbf ? (const u16*)p.out + p.qsz : p.nfb;   // bf16 source
  const float* o32 = (const float*)p.out;

  for (int i = t; i < NF; i += 256) qs[i] = qsrc[(long)g*qstride + i];
  if (t == 0){ sM = -1e30f; sZ = 0.0f; sSc = 1.0f; }
  int n0 = p.segS[g], n1 = p.segE[g];
  n0 = max(n0, 0); n1 = min(n1, p.N);
  float acc0 = 0.f, acc1 = 0.f;
  __syncthreads();

  for (int base = n0; base < n1; base += 32){
    const int cnt = min(32, n1 - base);
    {
      const int i = t >> 3, q8 = t & 7;
      if (i < cnt){
        if (bftile){
          const bfx8* src = (const bfx8*)(nbase + (long)(base + i)*NF + q8*48);
          #pragma unroll
          for (int j8 = 0; j8 < 6; ++j8)
            *(bfx8*)&nb[i*NF + q8*48 + j8*8] = __builtin_nontemporal_load(src + j8);
        } else {
          const f32x4* src = (const f32x4*)(o32 + p.qsz + (long)(base + i)*NF + q8*48);
          #pragma unroll
          for (int j4 = 0; j4 < 12; ++j4)
            *(f32x4*)&nfl[i*NF + q8*48 + j4*4] = __builtin_nontemporal_load(src + j4);
        }
      }
    }
    __syncthreads();
    {
      const int w = t >> 6, lane = t & 63;
      for (int ii = w; ii < cnt; ii += 4){
        float dot = 0.f;
        #pragma unroll
        for (int j = 0; j < 6; ++j){
          const int d = lane + 64*j;
          const float v = bftile ? bf2f(nb[ii*NF + d]) : nfl[ii*NF + d];
          dot = fmaf(v, qs[d], dot);
        }
        #pragma unroll
        for (int off = 32; off; off >>= 1) dot += __shfl_xor(dot, off);
        if (lane == 0) att[ii] = dot;
      }
    }
    __syncthreads();
    if (t < 32){
      const float l = (t < cnt) ? att[t] : -1e30f;
      float m = l;
      #pragma unroll
      for (int off = 16; off; off >>= 1) m = fmaxf(m, __shfl_xor(m, off));
      const float mnew = fmaxf(sM, m);
      const float e = (t < cnt) ? __expf(l - mnew) : 0.f;
      float z = e;
      #pragma unroll
      for (int off = 16; off; off >>= 1) z += __shfl_xor(z, off);
      if (t < cnt) att[t] = e;
      if (t == 0){
        const float sc = __expf(sM - mnew);
        sSc = sc; sZ = sZ * sc + z; sM = mnew;
      }
    }
    __syncthreads();
    {
      const float sc = sSc;
      acc0 *= sc; acc1 *= sc;
      for (int ii = 0; ii < cnt; ++ii){
        const float a = att[ii];
        const float v0 = bftile ? bf2f(nb[ii*NF + t]) : nfl[ii*NF + t];
        acc0 = fmaf(a, v0, acc0);
        if (t < 128){
          const float v1 = bftile ? bf2f(nb[ii*NF + 256 + t]) : nfl[ii*NF + 256 + t];
          acc1 = fmaf(a, v1, acc1);
        }
      }
    }
    __syncthreads();
  }

  const float invZ = (sZ != 0.0f) ? 1.0f / sZ : 0.0f;
  const float p0 = acc0 * invZ, p1 = acc1 * invZ;
  p.pooled[(long)g*NF + t] = p0;
  if (t < 128) p.pooled[(long)g*NF + 256 + t] = p1;
  if (finalstep){
    const long rb = (long)g * K2F;
    if (isbf){
      u16* o = (u16*)p.out;
      o[rb + t] = f2bf(qs[t]);
      if (t < 128) o[rb + 256 + t] = f2bf(qs[256 + t]);
      o[rb + NF + t] = f2bf(p0);
      if (t < 128) o[rb + NF + 256 + t] = f2bf(p1);
    } else {
      float* o = (float*)p.out;
      o[rb + t] = qs[t];
      if (t < 128) o[rb + 256 + t] = qs[256 + t];
      o[rb + NF + t] = p0;
      if (t < 128) o[rb + NF + 256 + t] = p1;
    }
  }
}

// ---------------- xcat = [h | pooled] (bf16) ----------------
__global__ void k_xcat(P p, const float* __restrict__ hsrc, int hstride){
  const int d2 = (int)blockIdx.x * 256 + threadIdx.x;   // grid.x = 3
  const int g  = (int)blockIdx.y;
  if (d2 >= K2F) return;
  const float v = (d2 < NF) ? hsrc[(long)g*hstride + d2]
                            : p.pooled[(long)g*NF + d2 - NF];
  p.xcatB[(long)g*K2F + d2] = f2bf(v);
}

// ---------------- LSTM GEMM (MFMA): gout = xcatB @ WcatB^T + bsum ----------------
__global__ __launch_bounds__(256, 4) void k_gemm_mfma(P p){
  __shared__ u16 aT[64*128];
  const int t = (int)threadIdx.x;
  const int lane = t & 63, w = t >> 6, cL = lane & 15;
  const int row0 = (int)blockIdx.x * 64, col0 = (int)blockIdx.y * 128;

  f32x4 acc[2][4];
  #pragma unroll
  for (int nt = 0; nt < 2; ++nt)
    #pragma unroll
    for (int m = 0; m < 4; ++m) acc[nt][m] = {0.f,0.f,0.f,0.f};

  for (int kc = 0; kc < K2F; kc += 128){
    __syncthreads();                        // prior chunk reads done
    { // stage A-tile [64][128] swizzled
      const int row = t >> 2, seg = t & 3;
      const int gr = row0 + row;
      const u16* src = p.xcatB + (long)gr*K2F + kc + seg*32;
      #pragma unroll
      for (int i = 0; i < 4; ++i){
        const int col = seg*32 + i*8;
        const int byte = (row*256 + col*2) ^ ((row&7)<<4);
        bfx8 v = {0,0,0,0,0,0,0,0};
        if (gr < p.B) v = *(const bfx8*)(src + i*8);
        *(bfx8*)((char*)aT + byte) = v;
      }
    }
    __syncthreads();
    for (int k0 = 0; k0 < 128; k0 += 32){
      bf16x8 bv[2];
      #pragma unroll
      for (int nt = 0; nt < 2; ++nt)
        bv[nt] = ldBs(p.WcatB, K2F, col0 + w*32 + nt*16, kc + k0, lane);
      bf16x8 a[4];
      #pragma unroll
      for (int m = 0; m < 4; ++m) a[m] = ldA(aT, m*16, k0, lane);
      #pragma unroll
      for (int nt = 0; nt < 2; ++nt)
        #pragma unroll
        for (int m = 0; m < 4; ++m) acc[nt][m] = MF(a[m], bv[nt], acc[nt][m]);
    }
  }
  // epilogue: += bsum, write gout f32
  #pragma unroll
  for (int nt = 0; nt < 2; ++nt){
    const int col = col0 + w*32 + nt*16 + cL;
    const float bs = p.bsum[col];
    #pragma unroll
    for (int m = 0; m < 4; ++m)
      #pragma unroll
      for (int j = 0; j < 4; ++j){
        const int row = row0 + m*16 + (lane>>4)*4 + j;
        if (row < p.B) p.gout[(long)row*NG4 + col] = acc[nt][m][j] + bs;
      }
  }
}

// ---------------- LSTM gate combine ----------------
__global__ void k_gates(P p, const float* __restrict__ csrc, int cstride){
  const long idx = (long)blockIdx.x * 256 + threadIdx.x;
  if (idx >= (long)p.B * NF) return;
  const int g = (int)(idx / NF), d = (int)(idx - (long)g*NF);
  const float* gr = p.gout + (long)g*NG4;
  const float i_ = fsig(gr[d]);
  const float f_ = fsig(gr[NF + d]);
  const float gc = ftanh(gr[2*NF + d]);
  const float o_ = fsig(gr[3*NF + d]);
  const float cp = csrc[(long)g*cstride + d];
  const float cn = fmaf(f_, cp, i_ * gc);
  p.cbuf[(long)g*NF + d] = cn;
  p.hbuf[(long)g*NF + d] = o_ * ftanh(cn);
}

// ---------------- host ----------------
extern "C" void kernel_launch(void* const* d_in, const int* in_sizes, int n_in,
                              void* d_out, int out_size, void* d_ws, size_t ws_size,
                              hipStream_t stream){
  P p{};
  p.unit_type = (const int*)d_in[0];
  p.n2g  = (const int*)d_in[1];
  p.embed = d_in[2];  p.w1 = d_in[3];  p.b1 = d_in[4];  p.w2 = d_in[5];  p.b2 = d_in[6];
  p.gwih = d_in[7];  p.gwhh = d_in[8]; p.gbih = d_in[9]; p.gbhh = d_in[10];
  p.lwih = d_in[11]; p.lwhh = d_in[12]; p.lbih = d_in[13]; p.lbhh = d_in[14];

  const int N = in_sizes[0];
  const int B = (int)(((long)out_size - (long)N*NF) / K2F);
  p.N = N; p.B = B; p.embedN = in_sizes[2];
  p.out = d_out; p.qsz = (long)B * K2F;

  char* w = (char*)d_ws;
  size_t used = 0;
  auto alloc = [&](size_t bytes) -> char* {
    char* r = w + used;
    used += (bytes + 255) & ~(size_t)255;
    return r;
  };
  p.flag  = (int*)alloc(4);
  p.segS  = (int*)alloc((size_t)B*4);
  p.segE  = (int*)alloc((size_t)B*4);
  p.embedB= (u16*)  alloc((size_t)p.embedN*2);
  p.W1eb  = (u16*)  alloc(16384*2);
  p.W2b   = (u16*)  alloc(16384*2);
  p.Wihb  = (u16*)  alloc(49152*2);
  p.Whhb  = (u16*)  alloc(49152*2);
  p.b1f   = (float*)alloc(NH*4);
  p.b2f   = (float*)alloc(NH*4);
  p.bihG  = (float*)alloc(NF*4);
  p.bhhG  = (float*)alloc(NF*4);
  p.WcatB = (u16*)  alloc((size_t)NG4*K2F*2);
  p.bsum  = (float*)alloc(NG4*4);
  p.h1v   = (float*)alloc(NF*4);
  p.c1v   = (float*)alloc(NF*4);
  p.hbuf  = (float*)alloc((size_t)B*NF*4);
  p.cbuf  = (float*)alloc((size_t)B*NF*4);
  p.pooled= (float*)alloc((size_t)B*NF*4);
  p.xcatB = (u16*)  alloc((size_t)B*K2F*2);
  p.gout  = (float*)alloc((size_t)B*NG4*4);
  if (used > ws_size){
    (void)hipMemsetAsync(d_out, 0, (size_t)out_size * 2, stream);
    return;
  }
  // optional bf16 shadow of node_feature for attention reads (f32 mode only)
  const size_t nfbBytes = (size_t)N * NF * 2;
  if (used + nfbBytes + 256 <= ws_size){
    p.nfb = (u16*)alloc(nfbBytes);
    p.useNfb = 1;
  } else {
    p.nfb = (u16*)p.flag;   // unused; valid pointer
    p.useNfb = 0;
  }

  const long prepTot = (long)p.embedN + 16384 + 16384 + 49152 + 49152
                     + (long)NG4*K2F + NH + NH + NF + NF + NG4 + B;

  k_detect<<<1, 256, 0, stream>>>(p);
  k_prep  <<<(int)((prepTot + 255)/256), 256, 0, stream>>>(p);
  k_segb  <<<(N + 255)/256, 256, 0, stream>>>(p);
  k_stageA_mfma<<<(N + 63)/64, 256, 0, stream>>>(p);
  k_lstm0 <<<1, NF, 0, stream>>>(p);

  const dim3 gemmG((B + 63)/64, NG4/128);
  // Set2Set step 1 (q = broadcast h1)
  k_attn <<<B, 256, 0, stream>>>(p, p.h1v, 0, 0);
  k_xcat <<<dim3(3, B), 256, 0, stream>>>(p, p.h1v, 0);
  k_gemm_mfma<<<gemmG, 256, 0, stream>>>(p);
  k_gates<<<(int)(((long)B*NF + 255)/256), 256, 0, stream>>>(p, p.c1v, 0);
  // step 2
  k_attn <<<B, 256, 0, stream>>>(p, p.hbuf, NF, 0);
  k_xcat <<<dim3(3, B), 256, 0, stream>>>(p, p.hbuf, NF);
  k_gemm_mfma<<<gemmG, 256, 0, stream>>>(p);
  k_gates<<<(int)(((long)B*NF + 255)/256), 256, 0, stream>>>(p, p.cbuf, NF);
  // step 3 (final: writes q_star)
  k_attn <<<B, 256, 0, stream>>>(p, p.hbuf, NF, 1);
}

// Round 15
// 1947.804 us; speedup vs baseline: 1.6760x; 1.6760x over previous
//
#include <hip/hip_runtime.h>

typedef unsigned short u16;
typedef unsigned int   u32;
typedef u16 bfx8 __attribute__((ext_vector_type(8)));
typedef __bf16 bf16x8 __attribute__((ext_vector_type(8)));
typedef float  f32x4  __attribute__((ext_vector_type(4)));

#define NH  128          // hidden dim H
#define NF  384          // feature dim F = 3H
#define K2F 768          // 2F
#define NG4 1536         // 4F

__device__ __forceinline__ float bf2f(u16 u){ return __uint_as_float(((u32)u) << 16); }
__device__ __forceinline__ u16 f2bf(float f){
  __bf16 h = (__bf16)f;
  return __builtin_bit_cast(u16, h);
}
__device__ __forceinline__ float fsig(float x){ return 1.0f / (1.0f + __expf(-x)); }
__device__ __forceinline__ float ftanh(float x){ return 1.0f - 2.0f / (__expf(2.0f * x) + 1.0f); }

struct P {
  const int *unit_type, *n2g;
  const void *embed, *w1, *b1, *w2, *b2, *gwih, *gwhh, *gbih, *gbhh, *lwih, *lwhh, *lbih, *lbhh;
  int *flag, *segS, *segE;
  u16 *embedB;                           // bf16 embed table
  u16 *W1eb, *W2b, *Wihb, *Whhb;         // bf16 canonical weights (stage A)
  float *b1f, *b2f, *bihG, *bhhG;
  u16 *WcatB;                            // fused LSTM weight [1536][768] bf16
  float *bsum;                           // [1536]
  float *h1v, *c1v;                      // step-1 LSTM single row (broadcast)
  float *hbuf, *cbuf;                    // [B][384] f32
  u16 *xcatB;                            // [B][768] bf16 (written by k_attn)
  float *gout;                           // [B][1536] f32
  u16 *nfb;                              // optional bf16 shadow of node_feature
  int useNfb;
  void *out; long qsz;
  int N, B, embedN;
};

__device__ __forceinline__ float ldin(const void* p, long i, int isbf){
  return isbf ? bf2f(((const u16*)p)[i]) : ((const float*)p)[i];
}

// ---------------- dtype detector ----------------
__global__ void k_detect(P p){
  __shared__ int cnt;
  if (threadIdx.x == 0) cnt = 0;
  __syncthreads();
  const u32* w = (const u32*)p.embed;
  const int nw = p.embedN / 2;
  int bad = 0;
  for (int i = threadIdx.x; i < nw; i += blockDim.x){
    u32 v = w[i];
    float fhi = __uint_as_float(v & 0xffff0000u);
    float flo = __uint_as_float(v << 16);
    if (!(fabsf(fhi) < 2.0f)) bad++;
    if (!(fabsf(flo) < 2.0f)) bad++;
  }
  atomicAdd(&cnt, bad);
  __syncthreads();
  if (threadIdx.x == 0) *p.flag = (cnt == 0) ? 1 : 0;
}

// ---------------- weight canonicalization ----------------
__global__ void k_prep(P p){
  long o = (long)blockIdx.x * 256 + threadIdx.x;
  const int isbf = *p.flag;
  if (o < p.embedN){ p.embedB[o] = f2bf(ldin(p.embed, o, isbf)); return; } o -= p.embedN;
  if (o < 16384){ long cc = o >> 7, k = o & 127;
    float v = ldin(p.w1, cc*256 + k, isbf) + ldin(p.w1, cc*256 + 128 + k, isbf);
    p.W1eb[o] = f2bf(v); return; } o -= 16384;
  if (o < 16384){ p.W2b[o]  = f2bf(ldin(p.w2, o, isbf));   return; } o -= 16384;
  if (o < 49152){ p.Wihb[o] = f2bf(ldin(p.gwih, o, isbf)); return; } o -= 49152;
  if (o < 49152){ p.Whhb[o] = f2bf(ldin(p.gwhh, o, isbf)); return; } o -= 49152;
  if (o < (long)NG4*K2F){ long j = o / K2F, k = o - j*K2F;
    float v = ldin(p.lwih, o, isbf);
    if (k < NF) v += ldin(p.lwhh, j*NF + k, isbf);
    p.WcatB[o] = f2bf(v); return; } o -= (long)NG4*K2F;
  if (o < NH){ p.b1f[o] = ldin(p.b1, o, isbf); return; } o -= NH;
  if (o < NH){ p.b2f[o] = ldin(p.b2, o, isbf); return; } o -= NH;
  if (o < NF){ p.bihG[o] = ldin(p.gbih, o, isbf); return; } o -= NF;
  if (o < NF){ p.bhhG[o] = ldin(p.gbhh, o, isbf); return; } o -= NF;
  if (o < NG4){ p.bsum[o] = ldin(p.lbih, o, isbf) + ldin(p.lbhh, o, isbf); return; } o -= NG4;
  if (o < p.B){ p.segS[o] = 0; p.segE[o] = 0; }
}

__global__ void k_segb(P p){
  int i = (int)blockIdx.x * 256 + threadIdx.x;
  if (i >= p.N) return;
  int g = p.n2g[i];
  if (g < 0 || g >= p.B) return;
  if (i == 0        || p.n2g[i-1] != g) p.segS[g] = i;
  if (i == p.N - 1  || p.n2g[i+1] != g) p.segE[g] = i + 1;
}

// ================= MFMA helpers =================
__device__ __forceinline__ f32x4 MF(bf16x8 a, bf16x8 b, f32x4 c){
  return __builtin_amdgcn_mfma_f32_16x16x32_bf16(a, b, c, 0, 0, 0);
}
__device__ __forceinline__ bf16x8 ldA(const u16* buf, int m0, int k0, int lane){
  const int row = m0 + (lane & 15);
  const int byte = (row*256 + (k0 + (lane>>4)*8)*2) ^ ((row&7)<<4);
  return *(const bf16x8*)((const char*)buf + byte);
}
__device__ __forceinline__ bf16x8 ldB(const u16* __restrict__ W, int n0, int k0, int lane){
  return *(const bf16x8*)(W + (long)(n0 + (lane&15))*NH + k0 + (lane>>4)*8);
}
__device__ __forceinline__ bf16x8 ldBs(const u16* __restrict__ W, long stride,
                                       int n0, int k0, int lane){
  return *(const bf16x8*)(W + (long)(n0 + (lane&15))*stride + k0 + (lane>>4)*8);
}
__device__ __forceinline__ void stLDS(u16* buf, int row, int col, float v){
  const int byte = (row*256 + col*2) ^ ((row&7)<<4);
  *(u16*)((char*)buf + byte) = f2bf(v);
}
__device__ __forceinline__ float ldLDS(const u16* buf, int row, int col){
  const int byte = (row*256 + col*2) ^ ((row&7)<<4);
  return bf2f(*(const u16*)((const char*)buf + byte));
}
__device__ __forceinline__ u16 ldLDSraw(const u16* buf, int row, int col){
  const int byte = (row*256 + col*2) ^ ((row&7)<<4);
  return *(const u16*)((const char*)buf + byte);
}

// ================= stage A (MFMA; r13 structure — measured best) =================
// 64 nodes/block, one tile per block, 4 waves, 3 swizzled LDS tiles (48 KB).
__global__ __launch_bounds__(256, 3) void k_stageA_mfma(P p){
  __shared__ u16 hA[64*128];                // h (layer input), swizzled
  __shared__ u16 mA[64*128];                // m1, later z-gate
  __shared__ u16 gA[64*128];                // msg
  const int t = (int)threadIdx.x;
  const int lane = t & 63, w = t >> 6;
  const int node0 = (int)blockIdx.x * 64;
  const int cL = lane & 15;
  const int isbf = *p.flag;

  { // gather embeddings (bf16 table) -> hA
    const int row = t >> 2, seg = t & 3;
    const int node = min(node0 + row, p.N - 1);
    int ut = p.unit_type[node];
    ut = min(max(ut, 0), p.embedN/NH - 1);
    const u16* src = p.embedB + (long)ut*NH + seg*32;
    #pragma unroll
    for (int i = 0; i < 4; ++i){
      const int col = seg*32 + i*8;
      const int byte = (row*256 + col*2) ^ ((row&7)<<4);
      *(bfx8*)((char*)hA + byte) = *(const bfx8*)(src + i*8);
    }
  }
  __syncthreads();

  u16*   out16 = (u16*)p.out;
  float* out32 = (float*)p.out;

  #pragma unroll 1
  for (int l = 0; l < 3; ++l){
    // ---- P1: m1 = relu(h @ W1e^T + b1) -> mA
    {
      f32x4 acc[2][4];
      #pragma unroll
      for (int nt = 0; nt < 2; ++nt){
        const float b = p.b1f[w*32 + nt*16 + cL];
        #pragma unroll
        for (int m = 0; m < 4; ++m) acc[nt][m] = {b,b,b,b};
      }
      for (int k0 = 0; k0 < 128; k0 += 32){
        bf16x8 bv[2];
        #pragma unroll
        for (int nt = 0; nt < 2; ++nt) bv[nt] = ldB(p.W1eb, w*32 + nt*16, k0, lane);
        bf16x8 a[4];
        #pragma unroll
        for (int m = 0; m < 4; ++m) a[m] = ldA(hA, m*16, k0, lane);
        #pragma unroll
        for (int nt = 0; nt < 2; ++nt)
          #pragma unroll
          for (int m = 0; m < 4; ++m) acc[nt][m] = MF(a[m], bv[nt], acc[nt][m]);
      }
      #pragma unroll
      for (int nt = 0; nt < 2; ++nt)
        #pragma unroll
        for (int m = 0; m < 4; ++m)
          #pragma unroll
          for (int j = 0; j < 4; ++j)
            stLDS(mA, m*16 + (lane>>4)*4 + j, w*32 + nt*16 + cL,
                  fmaxf(acc[nt][m][j], 0.0f));
    }
    __syncthreads();
    // ---- P2: msg = m1 @ W2^T + b2 -> gA
    {
      f32x4 acc[2][4];
      #pragma unroll
      for (int nt = 0; nt < 2; ++nt){
        const float b = p.b2f[w*32 + nt*16 + cL];
        #pragma unroll
        for (int m = 0; m < 4; ++m) acc[nt][m] = {b,b,b,b};
      }
      for (int k0 = 0; k0 < 128; k0 += 32){
        bf16x8 bv[2];
        #pragma unroll
        for (int nt = 0; nt < 2; ++nt) bv[nt] = ldB(p.W2b, w*32 + nt*16, k0, lane);
        bf16x8 a[4];
        #pragma unroll
        for (int m = 0; m < 4; ++m) a[m] = ldA(mA, m*16, k0, lane);
        #pragma unroll
        for (int nt = 0; nt < 2; ++nt)
          #pragma unroll
          for (int m = 0; m < 4; ++m) acc[nt][m] = MF(a[m], bv[nt], acc[nt][m]);
      }
      __syncthreads();              // all waves done reading mA
      #pragma unroll
      for (int nt = 0; nt < 2; ++nt)
        #pragma unroll
        for (int m = 0; m < 4; ++m)
          #pragma unroll
          for (int j = 0; j < 4; ++j)
            stLDS(gA, m*16 + (lane>>4)*4 + j, w*32 + nt*16 + cL, acc[nt][m][j]);
    }
    __syncthreads();
    // ---- P3 pass A: sr (tiles 0,1) and sz (tiles 2,3); gi+gh fused
    f32x4 rr[2][4];
    {
      f32x4 acc[4][4];
      #pragma unroll
      for (int tc = 0; tc < 4; ++tc){
        const int col = (tc < 2 ? 0 : 128) + w*32 + (tc&1)*16 + cL;
        const float b = p.bihG[col] + p.bhhG[col];
        #pragma unroll
        for (int m = 0; m < 4; ++m) acc[tc][m] = {b,b,b,b};
      }
      for (int k0 = 0; k0 < 128; k0 += 32){
        bf16x8 bv[4];
        #pragma unroll
        for (int tc = 0; tc < 4; ++tc)
          bv[tc] = ldB(p.Wihb, (tc < 2 ? 0 : 128) + w*32 + (tc&1)*16, k0, lane);
        bf16x8 a[4];
        #pragma unroll
        for (int m = 0; m < 4; ++m) a[m] = ldA(gA, m*16, k0, lane);
        #pragma unroll
        for (int tc = 0; tc < 4; ++tc)
          #pragma unroll
          for (int m = 0; m < 4; ++m) acc[tc][m] = MF(a[m], bv[tc], acc[tc][m]);
      }
      for (int k0 = 0; k0 < 128; k0 += 32){
        bf16x8 bv[4];
        #pragma unroll
        for (int tc = 0; tc < 4; ++tc)
          bv[tc] = ldB(p.Whhb, (tc < 2 ? 0 : 128) + w*32 + (tc&1)*16, k0, lane);
        bf16x8 a[4];
        #pragma unroll
        for (int m = 0; m < 4; ++m) a[m] = ldA(hA, m*16, k0, lane);
        #pragma unroll
        for (int tc = 0; tc < 4; ++tc)
          #pragma unroll
          for (int m = 0; m < 4; ++m) acc[tc][m] = MF(a[m], bv[tc], acc[tc][m]);
      }
      // r -> registers, z -> mA (bf16; m1 is dead)
      #pragma unroll
      for (int nt = 0; nt < 2; ++nt)
        #pragma unroll
        for (int m = 0; m < 4; ++m)
          #pragma unroll
          for (int j = 0; j < 4; ++j){
            rr[nt][m][j] = fsig(acc[nt][m][j]);
            stLDS(mA, m*16 + (lane>>4)*4 + j, w*32 + nt*16 + cL,
                  fsig(acc[nt+2][m][j]));
          }
    }
    // ---- P3 pass B: inn = msg@Wih_n + bih_n ; hn = h@Whh_n + bhh_n
    {
      f32x4 inn[2][4], hnn[2][4];
      #pragma unroll
      for (int nt = 0; nt < 2; ++nt){
        const int col = 256 + w*32 + nt*16 + cL;
        const float bi = p.bihG[col], bh = p.bhhG[col];
        #pragma unroll
        for (int m = 0; m < 4; ++m){ inn[nt][m] = {bi,bi,bi,bi}; hnn[nt][m] = {bh,bh,bh,bh}; }
      }
      for (int k0 = 0; k0 < 128; k0 += 32){
        bf16x8 bv[2];
        #pragma unroll
        for (int nt = 0; nt < 2; ++nt) bv[nt] = ldB(p.Wihb, 256 + w*32 + nt*16, k0, lane);
        bf16x8 a[4];
        #pragma unroll
        for (int m = 0; m < 4; ++m) a[m] = ldA(gA, m*16, k0, lane);
        #pragma unroll
        for (int nt = 0; nt < 2; ++nt)
          #pragma unroll
          for (int m = 0; m < 4; ++m) inn[nt][m] = MF(a[m], bv[nt], inn[nt][m]);
      }
      for (int k0 = 0; k0 < 128; k0 += 32){
        bf16x8 bv[2];
        #pragma unroll
        for (int nt = 0; nt < 2; ++nt) bv[nt] = ldB(p.Whhb, 256 + w*32 + nt*16, k0, lane);
        bf16x8 a[4];
        #pragma unroll
        for (int m = 0; m < 4; ++m) a[m] = ldA(hA, m*16, k0, lane);
        #pragma unroll
        for (int nt = 0; nt < 2; ++nt)
          #pragma unroll
          for (int m = 0; m < 4; ++m) hnn[nt][m] = MF(a[m], bv[nt], hnn[nt][m]);
      }
      // GRU combine, then barrier, then write hnew -> hA
      #pragma unroll
      for (int nt = 0; nt < 2; ++nt)
        #pragma unroll
        for (int m = 0; m < 4; ++m)
          #pragma unroll
          for (int j = 0; j < 4; ++j){
            const int row = m*16 + (lane>>4)*4 + j;
            const int col = w*32 + nt*16 + cL;
            const float nn = ftanh(fmaf(rr[nt][m][j], hnn[nt][m][j], inn[nt][m][j]));
            const float zv = ldLDS(mA, row, col);
            const float hv = ldLDS(hA, row, col);
            inn[nt][m][j] = fmaf(zv, hv - nn, nn);   // (1-z)*n + z*h
          }
      __syncthreads();
      #pragma unroll
      for (int nt = 0; nt < 2; ++nt)
        #pragma unroll
        for (int m = 0; m < 4; ++m)
          #pragma unroll
          for (int j = 0; j < 4; ++j)
            stLDS(hA, m*16 + (lane>>4)*4 + j, w*32 + nt*16 + cL, inn[nt][m][j]);
      __syncthreads();
    }
    // ---- Epilogue: coalesced non-temporal node_feature write from hA
    {
      const int col = t & 127;
      const int rh  = t >> 7;
      #pragma unroll 4
      for (int rb = 0; rb < 64; rb += 2){
        const int row = rb + rh;
        const int node = node0 + row;
        if (node < p.N){
          const u16 hv16 = ldLDSraw(hA, row, col);
          const long fi = (long)node*NF + l*NH + col;
          if (isbf){
            __builtin_nontemporal_store(hv16, &out16[p.qsz + fi]);
          } else {
            __builtin_nontemporal_store(bf2f(hv16), &out32[p.qsz + fi]);
            if (p.useNfb) __builtin_nontemporal_store(hv16, &p.nfb[fi]);
          }
        }
      }
    }
    // next P1 reads hA / writes mA only (mA last read before barrier)
  }
}

// ---------------- step-1 LSTM (inputs identically zero -> one row) ----------------
__global__ void k_lstm0(P p){
  const int d = (int)threadIdx.x;
  if (d >= NF) return;
  const float i_ = fsig(p.bsum[d]);
  const float gc = ftanh(p.bsum[2*NF + d]);
  const float o_ = fsig(p.bsum[3*NF + d]);
  const float cn = i_ * gc;                 // c0 = 0
  p.c1v[d] = cn;
  p.h1v[d] = o_ * ftanh(cn);
}

// ---------------- attention / Set2Set readout (one block per graph) ----------------
// Writes xcatB = [h | pooled] bf16 directly (non-final) or q_star (final).
__global__ __launch_bounds__(256) void k_attn(P p, const float* __restrict__ qsrc,
                                              int qstride, int finalstep){
  __shared__ alignas(16) char raw[32 * NF * 4];     // 48 KB tile: bf16 or f32
  __shared__ float qs[NF];
  __shared__ float att[32];
  __shared__ float sM, sZ, sSc;

  u16*   nb = (u16*)raw;
  float* nfl = (float*)raw;
  const int t = (int)threadIdx.x;
  const int g = (int)blockIdx.x;
  const int isbf = *p.flag;
  const int bftile = isbf | p.useNfb;
  const u16* nbase = isbf ? (const u16*)p.out + p.qsz : p.nfb;   // bf16 source
  const float* o32 = (const float*)p.out;

  for (int i = t; i < NF; i += 256) qs[i] = qsrc[(long)g*qstride + i];
  if (t == 0){ sM = -1e30f; sZ = 0.0f; sSc = 1.0f; }
  int n0 = p.segS[g], n1 = p.segE[g];
  n0 = max(n0, 0); n1 = min(n1, p.N);
  float acc0 = 0.f, acc1 = 0.f;
  __syncthreads();

  for (int base = n0; base < n1; base += 32){
    const int cnt = min(32, n1 - base);
    {
      const int i = t >> 3, q8 = t & 7;
      if (i < cnt){
        if (bftile){
          const bfx8* src = (const bfx8*)(nbase + (long)(base + i)*NF + q8*48);
          #pragma unroll
          for (int j8 = 0; j8 < 6; ++j8)
            *(bfx8*)&nb[i*NF + q8*48 + j8*8] = __builtin_nontemporal_load(src + j8);
        } else {
          const f32x4* src = (const f32x4*)(o32 + p.qsz + (long)(base + i)*NF + q8*48);
          #pragma unroll
          for (int j4 = 0; j4 < 12; ++j4)
            *(f32x4*)&nfl[i*NF + q8*48 + j4*4] = __builtin_nontemporal_load(src + j4);
        }
      }
    }
    __syncthreads();
    {
      const int w = t >> 6, lane = t & 63;
      for (int ii = w; ii < cnt; ii += 4){
        float dot = 0.f;
        #pragma unroll
        for (int j = 0; j < 6; ++j){
          const int d = lane + 64*j;
          const float v = bftile ? bf2f(nb[ii*NF + d]) : nfl[ii*NF + d];
          dot = fmaf(v, qs[d], dot);
        }
        #pragma unroll
        for (int off = 32; off; off >>= 1) dot += __shfl_xor(dot, off);
        if (lane == 0) att[ii] = dot;
      }
    }
    __syncthreads();
    if (t < 32){
      const float l = (t < cnt) ? att[t] : -1e30f;
      float m = l;
      #pragma unroll
      for (int off = 16; off; off >>= 1) m = fmaxf(m, __shfl_xor(m, off));
      const float mnew = fmaxf(sM, m);
      const float e = (t < cnt) ? __expf(l - mnew) : 0.f;
      float z = e;
      #pragma unroll
      for (int off = 16; off; off >>= 1) z += __shfl_xor(z, off);
      if (t < cnt) att[t] = e;
      if (t == 0){
        const float sc = __expf(sM - mnew);
        sSc = sc; sZ = sZ * sc + z; sM = mnew;
      }
    }
    __syncthreads();
    {
      const float sc = sSc;
      acc0 *= sc; acc1 *= sc;
      for (int ii = 0; ii < cnt; ++ii){
        const float a = att[ii];
        const float v0 = bftile ? bf2f(nb[ii*NF + t]) : nfl[ii*NF + t];
        acc0 = fmaf(a, v0, acc0);
        if (t < 128){
          const float v1 = bftile ? bf2f(nb[ii*NF + 256 + t]) : nfl[ii*NF + 256 + t];
          acc1 = fmaf(a, v1, acc1);
        }
      }
    }
    __syncthreads();
  }

  const float invZ = (sZ != 0.0f) ? 1.0f / sZ : 0.0f;
  const float p0 = acc0 * invZ, p1 = acc1 * invZ;
  if (!finalstep){
    u16* xr = p.xcatB + (long)g * K2F;
    xr[t] = f2bf(qs[t]);
    if (t < 128) xr[256 + t] = f2bf(qs[256 + t]);
    xr[NF + t] = f2bf(p0);
    if (t < 128) xr[NF + 256 + t] = f2bf(p1);
  } else {
    const long rb = (long)g * K2F;
    if (isbf){
      u16* o = (u16*)p.out;
      o[rb + t] = f2bf(qs[t]);
      if (t < 128) o[rb + 256 + t] = f2bf(qs[256 + t]);
      o[rb + NF + t] = f2bf(p0);
      if (t < 128) o[rb + NF + 256 + t] = f2bf(p1);
    } else {
      float* o = (float*)p.out;
      o[rb + t] = qs[t];
      if (t < 128) o[rb + 256 + t] = qs[256 + t];
      o[rb + NF + t] = p0;
      if (t < 128) o[rb + NF + 256 + t] = p1;
    }
  }
}

// ---------------- LSTM GEMM (MFMA): gout = xcatB @ WcatB^T + bsum ----------------
__global__ __launch_bounds__(256, 4) void k_gemm_mfma(P p){
  __shared__ u16 aT[64*128];
  const int t = (int)threadIdx.x;
  const int lane = t & 63, w = t >> 6, cL = lane & 15;
  const int row0 = (int)blockIdx.x * 64, col0 = (int)blockIdx.y * 128;

  f32x4 acc[2][4];
  #pragma unroll
  for (int nt = 0; nt < 2; ++nt)
    #pragma unroll
    for (int m = 0; m < 4; ++m) acc[nt][m] = {0.f,0.f,0.f,0.f};

  for (int kc = 0; kc < K2F; kc += 128){
    __syncthreads();                        // prior chunk reads done
    { // stage A-tile [64][128] swizzled
      const int row = t >> 2, seg = t & 3;
      const int gr = row0 + row;
      const u16* src = p.xcatB + (long)gr*K2F + kc + seg*32;
      #pragma unroll
      for (int i = 0; i < 4; ++i){
        const int col = seg*32 + i*8;
        const int byte = (row*256 + col*2) ^ ((row&7)<<4);
        bfx8 v = {0,0,0,0,0,0,0,0};
        if (gr < p.B) v = *(const bfx8*)(src + i*8);
        *(bfx8*)((char*)aT + byte) = v;
      }
    }
    __syncthreads();
    for (int k0 = 0; k0 < 128; k0 += 32){
      bf16x8 bv[2];
      #pragma unroll
      for (int nt = 0; nt < 2; ++nt)
        bv[nt] = ldBs(p.WcatB, K2F, col0 + w*32 + nt*16, kc + k0, lane);
      bf16x8 a[4];
      #pragma unroll
      for (int m = 0; m < 4; ++m) a[m] = ldA(aT, m*16, k0, lane);
      #pragma unroll
      for (int nt = 0; nt < 2; ++nt)
        #pragma unroll
        for (int m = 0; m < 4; ++m) acc[nt][m] = MF(a[m], bv[nt], acc[nt][m]);
    }
  }
  // epilogue: += bsum, write gout f32
  #pragma unroll
  for (int nt = 0; nt < 2; ++nt){
    const int col = col0 + w*32 + nt*16 + cL;
    const float bs = p.bsum[col];
    #pragma unroll
    for (int m = 0; m < 4; ++m)
      #pragma unroll
      for (int j = 0; j < 4; ++j){
        const int row = row0 + m*16 + (lane>>4)*4 + j;
        if (row < p.B) p.gout[(long)row*NG4 + col] = acc[nt][m][j] + bs;
      }
  }
}

// ---------------- LSTM gate combine ----------------
__global__ void k_gates(P p, const float* __restrict__ csrc, int cstride){
  const long idx = (long)blockIdx.x * 256 + threadIdx.x;
  if (idx >= (long)p.B * NF) return;
  const int g = (int)(idx / NF), d = (int)(idx - (long)g*NF);
  const float* gr = p.gout + (long)g*NG4;
  const float i_ = fsig(gr[d]);
  const float f_ = fsig(gr[NF + d]);
  const float gc = ftanh(gr[2*NF + d]);
  const float o_ = fsig(gr[3*NF + d]);
  const float cp = csrc[(long)g*cstride + d];
  const float cn = fmaf(f_, cp, i_ * gc);
  p.cbuf[(long)g*NF + d] = cn;
  p.hbuf[(long)g*NF + d] = o_ * ftanh(cn);
}

// ---------------- host ----------------
extern "C" void kernel_launch(void* const* d_in, const int* in_sizes, int n_in,
                              void* d_out, int out_size, void* d_ws, size_t ws_size,
                              hipStream_t stream){
  P p{};
  p.unit_type = (const int*)d_in[0];
  p.n2g  = (const int*)d_in[1];
  p.embed = d_in[2];  p.w1 = d_in[3];  p.b1 = d_in[4];  p.w2 = d_in[5];  p.b2 = d_in[6];
  p.gwih = d_in[7];  p.gwhh = d_in[8]; p.gbih = d_in[9]; p.gbhh = d_in[10];
  p.lwih = d_in[11]; p.lwhh = d_in[12]; p.lbih = d_in[13]; p.lbhh = d_in[14];

  const int N = in_sizes[0];
  const int B = (int)(((long)out_size - (long)N*NF) / K2F);
  p.N = N; p.B = B; p.embedN = in_sizes[2];
  p.out = d_out; p.qsz = (long)B * K2F;

  char* w = (char*)d_ws;
  size_t used = 0;
  auto alloc = [&](size_t bytes) -> char* {
    char* r = w + used;
    used += (bytes + 255) & ~(size_t)255;
    return r;
  };
  p.flag  = (int*)alloc(4);
  p.segS  = (int*)alloc((size_t)B*4);
  p.segE  = (int*)alloc((size_t)B*4);
  p.embedB= (u16*)  alloc((size_t)p.embedN*2);
  p.W1eb  = (u16*)  alloc(16384*2);
  p.W2b   = (u16*)  alloc(16384*2);
  p.Wihb  = (u16*)  alloc(49152*2);
  p.Whhb  = (u16*)  alloc(49152*2);
  p.b1f   = (float*)alloc(NH*4);
  p.b2f   = (float*)alloc(NH*4);
  p.bihG  = (float*)alloc(NF*4);
  p.bhhG  = (float*)alloc(NF*4);
  p.WcatB = (u16*)  alloc((size_t)NG4*K2F*2);
  p.bsum  = (float*)alloc(NG4*4);
  p.h1v   = (float*)alloc(NF*4);
  p.c1v   = (float*)alloc(NF*4);
  p.hbuf  = (float*)alloc((size_t)B*NF*4);
  p.cbuf  = (float*)alloc((size_t)B*NF*4);
  p.xcatB = (u16*)  alloc((size_t)B*K2F*2);
  p.gout  = (float*)alloc((size_t)B*NG4*4);
  if (used > ws_size){
    (void)hipMemsetAsync(d_out, 0, (size_t)out_size * 2, stream);
    return;
  }
  // optional bf16 shadow of node_feature for attention reads (f32 mode only)
  const size_t nfbBytes = (size_t)N * NF * 2;
  if (used + nfbBytes + 256 <= ws_size){
    p.nfb = (u16*)alloc(nfbBytes);
    p.useNfb = 1;
  } else {
    p.nfb = (u16*)p.flag;   // unused; valid pointer
    p.useNfb = 0;
  }

  const long prepTot = (long)p.embedN + 16384 + 16384 + 49152 + 49152
                     + (long)NG4*K2F + NH + NH + NF + NF + NG4 + B;

  k_detect<<<1, 256, 0, stream>>>(p);
  k_prep  <<<(int)((prepTot + 255)/256), 256, 0, stream>>>(p);
  k_segb  <<<(N + 255)/256, 256, 0, stream>>>(p);
  k_stageA_mfma<<<(N + 63)/64, 256, 0, stream>>>(p);
  k_lstm0 <<<1, NF, 0, stream>>>(p);

  const dim3 gemmG((B + 63)/64, NG4/128);
  // Set2Set step 1 (q = broadcast h1); attn writes xcatB directly
  k_attn <<<B, 256, 0, stream>>>(p, p.h1v, 0, 0);
  k_gemm_mfma<<<gemmG, 256, 0, stream>>>(p);
  k_gates<<<(int)(((long)B*NF + 255)/256), 256, 0, stream>>>(p, p.c1v, 0);
  // step 2
  k_attn <<<B, 256, 0, stream>>>(p, p.hbuf, NF, 0);
  k_gemm_mfma<<<gemmG, 256, 0, stream>>>(p);
  k_gates<<<(int)(((long)B*NF + 255)/256), 256, 0, stream>>>(p, p.cbuf, NF);
  // step 3 (final: writes q_star)
  k_attn <<<B, 256, 0, stream>>>(p, p.hbuf, NF, 1);
}

// Round 16
// 1915.736 us; speedup vs baseline: 1.7041x; 1.0167x over previous
//
#include <hip/hip_runtime.h>

typedef unsigned short u16;
typedef unsigned int   u32;
typedef u16 bfx8 __attribute__((ext_vector_type(8)));
typedef __bf16 bf16x8 __attribute__((ext_vector_type(8)));
typedef float  f32x4  __attribute__((ext_vector_type(4)));

#define NH  128          // hidden dim H
#define NF  384          // feature dim F = 3H
#define K2F 768          // 2F
#define NG4 1536         // 4F

__device__ __forceinline__ float bf2f(u16 u){ return __uint_as_float(((u32)u) << 16); }
__device__ __forceinline__ u16 f2bf(float f){
  __bf16 h = (__bf16)f;
  return __builtin_bit_cast(u16, h);
}
__device__ __forceinline__ float fsig(float x){ return 1.0f / (1.0f + __expf(-x)); }
__device__ __forceinline__ float ftanh(float x){ return 1.0f - 2.0f / (__expf(2.0f * x) + 1.0f); }

struct P {
  const int *unit_type, *n2g;
  const void *embed, *w1, *b1, *w2, *b2, *gwih, *gwhh, *gbih, *gbhh, *lwih, *lwhh, *lbih, *lbhh;
  int *flag, *segS, *segE;
  u16 *embedB;                           // bf16 embed table
  u16 *W1eb, *W2b, *Wihb, *Whhb;         // bf16 canonical weights (stage A)
  float *b1f, *b2f, *bihG, *bhhG;
  u16 *WcatB;                            // fused LSTM weight [1536][768] bf16
  float *bsum;                           // [1536]
  float *h1v, *c1v;                      // step-1 LSTM single row (broadcast)
  float *hbuf, *cbuf;                    // [B][384] f32
  u16 *xcatB;                            // [B][768] bf16 (written by k_attn)
  u16 *nfb;                              // optional bf16 shadow of node_feature
  int useNfb;
  void *out; long qsz;
  int N, B, embedN;
};

__device__ __forceinline__ float ldin(const void* p, long i, int isbf){
  return isbf ? bf2f(((const u16*)p)[i]) : ((const float*)p)[i];
}

// ---------------- dtype detector ----------------
__global__ void k_detect(P p){
  __shared__ int cnt;
  if (threadIdx.x == 0) cnt = 0;
  __syncthreads();
  const u32* w = (const u32*)p.embed;
  const int nw = p.embedN / 2;
  int bad = 0;
  for (int i = threadIdx.x; i < nw; i += blockDim.x){
    u32 v = w[i];
    float fhi = __uint_as_float(v & 0xffff0000u);
    float flo = __uint_as_float(v << 16);
    if (!(fabsf(fhi) < 2.0f)) bad++;
    if (!(fabsf(flo) < 2.0f)) bad++;
  }
  atomicAdd(&cnt, bad);
  __syncthreads();
  if (threadIdx.x == 0) *p.flag = (cnt == 0) ? 1 : 0;
}

// ---------------- weight canonicalization (+ segment bounds, folded in) --------
__global__ void k_prep(P p){
  long o = (long)blockIdx.x * 256 + threadIdx.x;
  const int isbf = *p.flag;
  if (o < p.embedN){ p.embedB[o] = f2bf(ldin(p.embed, o, isbf)); return; } o -= p.embedN;
  if (o < 16384){ long cc = o >> 7, k = o & 127;
    float v = ldin(p.w1, cc*256 + k, isbf) + ldin(p.w1, cc*256 + 128 + k, isbf);
    p.W1eb[o] = f2bf(v); return; } o -= 16384;
  if (o < 16384){ p.W2b[o]  = f2bf(ldin(p.w2, o, isbf));   return; } o -= 16384;
  if (o < 49152){ p.Wihb[o] = f2bf(ldin(p.gwih, o, isbf)); return; } o -= 49152;
  if (o < 49152){ p.Whhb[o] = f2bf(ldin(p.gwhh, o, isbf)); return; } o -= 49152;
  if (o < (long)NG4*K2F){ long j = o / K2F, k = o - j*K2F;
    float v = ldin(p.lwih, o, isbf);
    if (k < NF) v += ldin(p.lwhh, j*NF + k, isbf);
    p.WcatB[o] = f2bf(v); return; } o -= (long)NG4*K2F;
  if (o < NH){ p.b1f[o] = ldin(p.b1, o, isbf); return; } o -= NH;
  if (o < NH){ p.b2f[o] = ldin(p.b2, o, isbf); return; } o -= NH;
  if (o < NF){ p.bihG[o] = ldin(p.gbih, o, isbf); return; } o -= NF;
  if (o < NF){ p.bhhG[o] = ldin(p.gbhh, o, isbf); return; } o -= NF;
  if (o < NG4){ p.bsum[o] = ldin(p.lbih, o, isbf) + ldin(p.lbhh, o, isbf); return; } o -= NG4;
  if (o < p.N){ // segment bounds (every graph non-empty per reference)
    const int i = (int)o;
    const int g = p.n2g[i];
    if (g >= 0 && g < p.B){
      if (i == 0        || p.n2g[i-1] != g) p.segS[g] = i;
      if (i == p.N - 1  || p.n2g[i+1] != g) p.segE[g] = i + 1;
    }
  }
}

// ================= MFMA helpers =================
__device__ __forceinline__ f32x4 MF(bf16x8 a, bf16x8 b, f32x4 c){
  return __builtin_amdgcn_mfma_f32_16x16x32_bf16(a, b, c, 0, 0, 0);
}
__device__ __forceinline__ bf16x8 ldA(const u16* buf, int m0, int k0, int lane){
  const int row = m0 + (lane & 15);
  const int byte = (row*256 + (k0 + (lane>>4)*8)*2) ^ ((row&7)<<4);
  return *(const bf16x8*)((const char*)buf + byte);
}
__device__ __forceinline__ bf16x8 ldB(const u16* __restrict__ W, int n0, int k0, int lane){
  return *(const bf16x8*)(W + (long)(n0 + (lane&15))*NH + k0 + (lane>>4)*8);
}
__device__ __forceinline__ bf16x8 ldBs(const u16* __restrict__ W, long stride,
                                       int n0, int k0, int lane){
  return *(const bf16x8*)(W + (long)(n0 + (lane&15))*stride + k0 + (lane>>4)*8);
}
__device__ __forceinline__ void stLDS(u16* buf, int row, int col, float v){
  const int byte = (row*256 + col*2) ^ ((row&7)<<4);
  *(u16*)((char*)buf + byte) = f2bf(v);
}
__device__ __forceinline__ float ldLDS(const u16* buf, int row, int col){
  const int byte = (row*256 + col*2) ^ ((row&7)<<4);
  return bf2f(*(const u16*)((const char*)buf + byte));
}
__device__ __forceinline__ u16 ldLDSraw(const u16* buf, int row, int col){
  const int byte = (row*256 + col*2) ^ ((row&7)<<4);
  return *(const u16*)((const char*)buf + byte);
}

// ================= stage A (MFMA; r13 structure — measured best) =================
// 64 nodes/block, one tile per block, 4 waves, 3 swizzled LDS tiles (48 KB).
__global__ __launch_bounds__(256, 3) void k_stageA_mfma(P p){
  __shared__ u16 hA[64*128];                // h (layer input), swizzled
  __shared__ u16 mA[64*128];                // m1, later z-gate
  __shared__ u16 gA[64*128];                // msg
  const int t = (int)threadIdx.x;
  const int lane = t & 63, w = t >> 6;
  const int node0 = (int)blockIdx.x * 64;
  const int cL = lane & 15;
  const int isbf = *p.flag;

  { // gather embeddings (bf16 table) -> hA
    const int row = t >> 2, seg = t & 3;
    const int node = min(node0 + row, p.N - 1);
    int ut = p.unit_type[node];
    ut = min(max(ut, 0), p.embedN/NH - 1);
    const u16* src = p.embedB + (long)ut*NH + seg*32;
    #pragma unroll
    for (int i = 0; i < 4; ++i){
      const int col = seg*32 + i*8;
      const int byte = (row*256 + col*2) ^ ((row&7)<<4);
      *(bfx8*)((char*)hA + byte) = *(const bfx8*)(src + i*8);
    }
  }
  __syncthreads();

  u16*   out16 = (u16*)p.out;
  float* out32 = (float*)p.out;

  #pragma unroll 1
  for (int l = 0; l < 3; ++l){
    // ---- P1: m1 = relu(h @ W1e^T + b1) -> mA
    {
      f32x4 acc[2][4];
      #pragma unroll
      for (int nt = 0; nt < 2; ++nt){
        const float b = p.b1f[w*32 + nt*16 + cL];
        #pragma unroll
        for (int m = 0; m < 4; ++m) acc[nt][m] = {b,b,b,b};
      }
      for (int k0 = 0; k0 < 128; k0 += 32){
        bf16x8 bv[2];
        #pragma unroll
        for (int nt = 0; nt < 2; ++nt) bv[nt] = ldB(p.W1eb, w*32 + nt*16, k0, lane);
        bf16x8 a[4];
        #pragma unroll
        for (int m = 0; m < 4; ++m) a[m] = ldA(hA, m*16, k0, lane);
        #pragma unroll
        for (int nt = 0; nt < 2; ++nt)
          #pragma unroll
          for (int m = 0; m < 4; ++m) acc[nt][m] = MF(a[m], bv[nt], acc[nt][m]);
      }
      #pragma unroll
      for (int nt = 0; nt < 2; ++nt)
        #pragma unroll
        for (int m = 0; m < 4; ++m)
          #pragma unroll
          for (int j = 0; j < 4; ++j)
            stLDS(mA, m*16 + (lane>>4)*4 + j, w*32 + nt*16 + cL,
                  fmaxf(acc[nt][m][j], 0.0f));
    }
    __syncthreads();
    // ---- P2: msg = m1 @ W2^T + b2 -> gA
    {
      f32x4 acc[2][4];
      #pragma unroll
      for (int nt = 0; nt < 2; ++nt){
        const float b = p.b2f[w*32 + nt*16 + cL];
        #pragma unroll
        for (int m = 0; m < 4; ++m) acc[nt][m] = {b,b,b,b};
      }
      for (int k0 = 0; k0 < 128; k0 += 32){
        bf16x8 bv[2];
        #pragma unroll
        for (int nt = 0; nt < 2; ++nt) bv[nt] = ldB(p.W2b, w*32 + nt*16, k0, lane);
        bf16x8 a[4];
        #pragma unroll
        for (int m = 0; m < 4; ++m) a[m] = ldA(mA, m*16, k0, lane);
        #pragma unroll
        for (int nt = 0; nt < 2; ++nt)
          #pragma unroll
          for (int m = 0; m < 4; ++m) acc[nt][m] = MF(a[m], bv[nt], acc[nt][m]);
      }
      __syncthreads();              // all waves done reading mA
      #pragma unroll
      for (int nt = 0; nt < 2; ++nt)
        #pragma unroll
        for (int m = 0; m < 4; ++m)
          #pragma unroll
          for (int j = 0; j < 4; ++j)
            stLDS(gA, m*16 + (lane>>4)*4 + j, w*32 + nt*16 + cL, acc[nt][m][j]);
    }
    __syncthreads();
    // ---- P3 pass A: sr (tiles 0,1) and sz (tiles 2,3); gi+gh fused
    f32x4 rr[2][4];
    {
      f32x4 acc[4][4];
      #pragma unroll
      for (int tc = 0; tc < 4; ++tc){
        const int col = (tc < 2 ? 0 : 128) + w*32 + (tc&1)*16 + cL;
        const float b = p.bihG[col] + p.bhhG[col];
        #pragma unroll
        for (int m = 0; m < 4; ++m) acc[tc][m] = {b,b,b,b};
      }
      for (int k0 = 0; k0 < 128; k0 += 32){
        bf16x8 bv[4];
        #pragma unroll
        for (int tc = 0; tc < 4; ++tc)
          bv[tc] = ldB(p.Wihb, (tc < 2 ? 0 : 128) + w*32 + (tc&1)*16, k0, lane);
        bf16x8 a[4];
        #pragma unroll
        for (int m = 0; m < 4; ++m) a[m] = ldA(gA, m*16, k0, lane);
        #pragma unroll
        for (int tc = 0; tc < 4; ++tc)
          #pragma unroll
          for (int m = 0; m < 4; ++m) acc[tc][m] = MF(a[m], bv[tc], acc[tc][m]);
      }
      for (int k0 = 0; k0 < 128; k0 += 32){
        bf16x8 bv[4];
        #pragma unroll
        for (int tc = 0; tc < 4; ++tc)
          bv[tc] = ldB(p.Whhb, (tc < 2 ? 0 : 128) + w*32 + (tc&1)*16, k0, lane);
        bf16x8 a[4];
        #pragma unroll
        for (int m = 0; m < 4; ++m) a[m] = ldA(hA, m*16, k0, lane);
        #pragma unroll
        for (int tc = 0; tc < 4; ++tc)
          #pragma unroll
          for (int m = 0; m < 4; ++m) acc[tc][m] = MF(a[m], bv[tc], acc[tc][m]);
      }
      // r -> registers, z -> mA (bf16; m1 is dead)
      #pragma unroll
      for (int nt = 0; nt < 2; ++nt)
        #pragma unroll
        for (int m = 0; m < 4; ++m)
          #pragma unroll
          for (int j = 0; j < 4; ++j){
            rr[nt][m][j] = fsig(acc[nt][m][j]);
            stLDS(mA, m*16 + (lane>>4)*4 + j, w*32 + nt*16 + cL,
                  fsig(acc[nt+2][m][j]));
          }
    }
    // ---- P3 pass B: inn = msg@Wih_n + bih_n ; hn = h@Whh_n + bhh_n
    {
      f32x4 inn[2][4], hnn[2][4];
      #pragma unroll
      for (int nt = 0; nt < 2; ++nt){
        const int col = 256 + w*32 + nt*16 + cL;
        const float bi = p.bihG[col], bh = p.bhhG[col];
        #pragma unroll
        for (int m = 0; m < 4; ++m){ inn[nt][m] = {bi,bi,bi,bi}; hnn[nt][m] = {bh,bh,bh,bh}; }
      }
      for (int k0 = 0; k0 < 128; k0 += 32){
        bf16x8 bv[2];
        #pragma unroll
        for (int nt = 0; nt < 2; ++nt) bv[nt] = ldB(p.Wihb, 256 + w*32 + nt*16, k0, lane);
        bf16x8 a[4];
        #pragma unroll
        for (int m = 0; m < 4; ++m) a[m] = ldA(gA, m*16, k0, lane);
        #pragma unroll
        for (int nt = 0; nt < 2; ++nt)
          #pragma unroll
          for (int m = 0; m < 4; ++m) inn[nt][m] = MF(a[m], bv[nt], inn[nt][m]);
      }
      for (int k0 = 0; k0 < 128; k0 += 32){
        bf16x8 bv[2];
        #pragma unroll
        for (int nt = 0; nt < 2; ++nt) bv[nt] = ldB(p.Whhb, 256 + w*32 + nt*16, k0, lane);
        bf16x8 a[4];
        #pragma unroll
        for (int m = 0; m < 4; ++m) a[m] = ldA(hA, m*16, k0, lane);
        #pragma unroll
        for (int nt = 0; nt < 2; ++nt)
          #pragma unroll
          for (int m = 0; m < 4; ++m) hnn[nt][m] = MF(a[m], bv[nt], hnn[nt][m]);
      }
      // GRU combine, then barrier, then write hnew -> hA
      #pragma unroll
      for (int nt = 0; nt < 2; ++nt)
        #pragma unroll
        for (int m = 0; m < 4; ++m)
          #pragma unroll
          for (int j = 0; j < 4; ++j){
            const int row = m*16 + (lane>>4)*4 + j;
            const int col = w*32 + nt*16 + cL;
            const float nn = ftanh(fmaf(rr[nt][m][j], hnn[nt][m][j], inn[nt][m][j]));
            const float zv = ldLDS(mA, row, col);
            const float hv = ldLDS(hA, row, col);
            inn[nt][m][j] = fmaf(zv, hv - nn, nn);   // (1-z)*n + z*h
          }
      __syncthreads();
      #pragma unroll
      for (int nt = 0; nt < 2; ++nt)
        #pragma unroll
        for (int m = 0; m < 4; ++m)
          #pragma unroll
          for (int j = 0; j < 4; ++j)
            stLDS(hA, m*16 + (lane>>4)*4 + j, w*32 + nt*16 + cL, inn[nt][m][j]);
      __syncthreads();
    }
    // ---- Epilogue: coalesced non-temporal node_feature write from hA
    {
      const int col = t & 127;
      const int rh  = t >> 7;
      #pragma unroll 4
      for (int rb = 0; rb < 64; rb += 2){
        const int row = rb + rh;
        const int node = node0 + row;
        if (node < p.N){
          const u16 hv16 = ldLDSraw(hA, row, col);
          const long fi = (long)node*NF + l*NH + col;
          if (isbf){
            __builtin_nontemporal_store(hv16, &out16[p.qsz + fi]);
          } else {
            __builtin_nontemporal_store(bf2f(hv16), &out32[p.qsz + fi]);
            if (p.useNfb) __builtin_nontemporal_store(hv16, &p.nfb[fi]);
          }
        }
      }
    }
    // next P1 reads hA / writes mA only (mA last read before barrier)
  }
}

// ---------------- step-1 LSTM (inputs identically zero -> one row) ----------------
__global__ void k_lstm0(P p){
  const int d = (int)threadIdx.x;
  if (d >= NF) return;
  const float i_ = fsig(p.bsum[d]);
  const float gc = ftanh(p.bsum[2*NF + d]);
  const float o_ = fsig(p.bsum[3*NF + d]);
  const float cn = i_ * gc;                 // c0 = 0
  p.c1v[d] = cn;
  p.h1v[d] = o_ * ftanh(cn);
}

// ---------------- attention / Set2Set readout (one block per graph) ----------------
// Writes xcatB = [h | pooled] bf16 directly (non-final) or q_star (final).
__global__ __launch_bounds__(256) void k_attn(P p, const float* __restrict__ qsrc,
                                              int qstride, int finalstep){
  __shared__ alignas(16) char raw[32 * NF * 4];     // 48 KB tile: bf16 or f32
  __shared__ float qs[NF];
  __shared__ float att[32];
  __shared__ float sM, sZ, sSc;

  u16*   nb = (u16*)raw;
  float* nfl = (float*)raw;
  const int t = (int)threadIdx.x;
  const int g = (int)blockIdx.x;
  const int isbf = *p.flag;
  const int bftile = isbf | p.useNfb;
  const u16* nbase = isbf ? (const u16*)p.out + p.qsz : p.nfb;   // bf16 source
  const float* o32 = (const float*)p.out;

  for (int i = t; i < NF; i += 256) qs[i] = qsrc[(long)g*qstride + i];
  if (t == 0){ sM = -1e30f; sZ = 0.0f; sSc = 1.0f; }
  int n0 = p.segS[g], n1 = p.segE[g];
  n0 = max(n0, 0); n1 = min(n1, p.N);
  float acc0 = 0.f, acc1 = 0.f;
  __syncthreads();

  for (int base = n0; base < n1; base += 32){
    const int cnt = min(32, n1 - base);
    {
      const int i = t >> 3, q8 = t & 7;
      if (i < cnt){
        if (bftile){
          const bfx8* src = (const bfx8*)(nbase + (long)(base + i)*NF + q8*48);
          #pragma unroll
          for (int j8 = 0; j8 < 6; ++j8)
            *(bfx8*)&nb[i*NF + q8*48 + j8*8] = __builtin_nontemporal_load(src + j8);
        } else {
          const f32x4* src = (const f32x4*)(o32 + p.qsz + (long)(base + i)*NF + q8*48);
          #pragma unroll
          for (int j4 = 0; j4 < 12; ++j4)
            *(f32x4*)&nfl[i*NF + q8*48 + j4*4] = __builtin_nontemporal_load(src + j4);
        }
      }
    }
    __syncthreads();
    {
      const int w = t >> 6, lane = t & 63;
      for (int ii = w; ii < cnt; ii += 4){
        float dot = 0.f;
        #pragma unroll
        for (int j = 0; j < 6; ++j){
          const int d = lane + 64*j;
          const float v = bftile ? bf2f(nb[ii*NF + d]) : nfl[ii*NF + d];
          dot = fmaf(v, qs[d], dot);
        }
        #pragma unroll
        for (int off = 32; off; off >>= 1) dot += __shfl_xor(dot, off);
        if (lane == 0) att[ii] = dot;
      }
    }
    __syncthreads();
    if (t < 32){
      const float l = (t < cnt) ? att[t] : -1e30f;
      float m = l;
      #pragma unroll
      for (int off = 16; off; off >>= 1) m = fmaxf(m, __shfl_xor(m, off));
      const float mnew = fmaxf(sM, m);
      const float e = (t < cnt) ? __expf(l - mnew) : 0.f;
      float z = e;
      #pragma unroll
      for (int off = 16; off; off >>= 1) z += __shfl_xor(z, off);
      if (t < cnt) att[t] = e;
      if (t == 0){
        const float sc = __expf(sM - mnew);
        sSc = sc; sZ = sZ * sc + z; sM = mnew;
      }
    }
    __syncthreads();
    {
      const float sc = sSc;
      acc0 *= sc; acc1 *= sc;
      for (int ii = 0; ii < cnt; ++ii){
        const float a = att[ii];
        const float v0 = bftile ? bf2f(nb[ii*NF + t]) : nfl[ii*NF + t];
        acc0 = fmaf(a, v0, acc0);
        if (t < 128){
          const float v1 = bftile ? bf2f(nb[ii*NF + 256 + t]) : nfl[ii*NF + 256 + t];
          acc1 = fmaf(a, v1, acc1);
        }
      }
    }
    __syncthreads();
  }

  const float invZ = (sZ != 0.0f) ? 1.0f / sZ : 0.0f;
  const float p0 = acc0 * invZ, p1 = acc1 * invZ;
  if (!finalstep){
    u16* xr = p.xcatB + (long)g * K2F;
    xr[t] = f2bf(qs[t]);
    if (t < 128) xr[256 + t] = f2bf(qs[256 + t]);
    xr[NF + t] = f2bf(p0);
    if (t < 128) xr[NF + 256 + t] = f2bf(p1);
  } else {
    const long rb = (long)g * K2F;
    if (isbf){
      u16* o = (u16*)p.out;
      o[rb + t] = f2bf(qs[t]);
      if (t < 128) o[rb + 256 + t] = f2bf(qs[256 + t]);
      o[rb + NF + t] = f2bf(p0);
      if (t < 128) o[rb + NF + 256 + t] = f2bf(p1);
    } else {
      float* o = (float*)p.out;
      o[rb + t] = qs[t];
      if (t < 128) o[rb + 256 + t] = qs[256 + t];
      o[rb + NF + t] = p0;
      if (t < 128) o[rb + NF + 256 + t] = p1;
    }
  }
}

// ---- fused LSTM GEMM + gate combine ----
// grid (B/64, NF/32). Block computes 64 rows x 32 dims x 4 gate quadrants
// (wave w = quadrant w), exchanges accumulators via LDS, applies the cell
// update, writes hbuf/cbuf directly. gout buffer + k_gates eliminated.
__global__ __launch_bounds__(256, 3) void k_gemm_fused(P p, const float* __restrict__ csrc,
                                                       int cstride){
  __shared__ u16 aT[64*128];
  __shared__ float xch[4*64*32];            // [quad][row][col] f32, 32 KB
  const int t = (int)threadIdx.x;
  const int lane = t & 63, w = t >> 6, cL = lane & 15;
  const int row0 = (int)blockIdx.x * 64;
  const int d0 = (int)blockIdx.y * 32;      // dim base within F

  f32x4 acc[2][4];
  #pragma unroll
  for (int nt = 0; nt < 2; ++nt)
    #pragma unroll
    for (int m = 0; m < 4; ++m) acc[nt][m] = {0.f,0.f,0.f,0.f};

  for (int kc = 0; kc < K2F; kc += 128){
    __syncthreads();                        // prior chunk reads done
    { // stage A-tile [64][128] swizzled
      const int row = t >> 2, seg = t & 3;
      const int gr = row0 + row;
      const u16* src = p.xcatB + (long)gr*K2F + kc + seg*32;
      #pragma unroll
      for (int i = 0; i < 4; ++i){
        const int col = seg*32 + i*8;
        const int byte = (row*256 + col*2) ^ ((row&7)<<4);
        bfx8 v = {0,0,0,0,0,0,0,0};
        if (gr < p.B) v = *(const bfx8*)(src + i*8);
        *(bfx8*)((char*)aT + byte) = v;
      }
    }
    __syncthreads();
    for (int k0 = 0; k0 < 128; k0 += 32){
      bf16x8 bv[2];
      #pragma unroll
      for (int nt = 0; nt < 2; ++nt)
        bv[nt] = ldBs(p.WcatB, K2F, w*NF + d0 + nt*16, kc + k0, lane);
      bf16x8 a[4];
      #pragma unroll
      for (int m = 0; m < 4; ++m) a[m] = ldA(aT, m*16, k0, lane);
      #pragma unroll
      for (int nt = 0; nt < 2; ++nt)
        #pragma unroll
        for (int m = 0; m < 4; ++m) acc[nt][m] = MF(a[m], bv[nt], acc[nt][m]);
    }
  }
  // exchange: wave w writes its quadrant's 64x32 accumulators (+bias)
  #pragma unroll
  for (int nt = 0; nt < 2; ++nt){
    const float bs = p.bsum[w*NF + d0 + nt*16 + cL];
    #pragma unroll
    for (int m = 0; m < 4; ++m)
      #pragma unroll
      for (int j = 0; j < 4; ++j){
        const int row = m*16 + (lane>>4)*4 + j;
        const int col = nt*16 + cL;
        xch[(w*64 + row)*32 + col] = acc[nt][m][j] + bs;
      }
  }
  __syncthreads();
  // combine: gate order i,f,g,o (quadrants 0..3)
  {
    const int col = t & 31;
    const int rb2 = (t >> 5) * 8;
    const int d = d0 + col;
    #pragma unroll
    for (int r = 0; r < 8; ++r){
      const int row = rb2 + r;
      const int grow = row0 + row;
      if (grow < p.B){
        const float i_ = fsig (xch[(0*64 + row)*32 + col]);
        const float f_ = fsig (xch[(1*64 + row)*32 + col]);
        const float g_ = ftanh(xch[(2*64 + row)*32 + col]);
        const float o_ = fsig (xch[(3*64 + row)*32 + col]);
        const float cp = csrc[(long)grow*cstride + d];
        const float cn = fmaf(f_, cp, i_ * g_);
        p.cbuf[(long)grow*NF + d] = cn;
        p.hbuf[(long)grow*NF + d] = o_ * ftanh(cn);
      }
    }
  }
}

// ---------------- host ----------------
extern "C" void kernel_launch(void* const* d_in, const int* in_sizes, int n_in,
                              void* d_out, int out_size, void* d_ws, size_t ws_size,
                              hipStream_t stream){
  P p{};
  p.unit_type = (const int*)d_in[0];
  p.n2g  = (const int*)d_in[1];
  p.embed = d_in[2];  p.w1 = d_in[3];  p.b1 = d_in[4];  p.w2 = d_in[5];  p.b2 = d_in[6];
  p.gwih = d_in[7];  p.gwhh = d_in[8]; p.gbih = d_in[9]; p.gbhh = d_in[10];
  p.lwih = d_in[11]; p.lwhh = d_in[12]; p.lbih = d_in[13]; p.lbhh = d_in[14];

  const int N = in_sizes[0];
  const int B = (int)(((long)out_size - (long)N*NF) / K2F);
  p.N = N; p.B = B; p.embedN = in_sizes[2];
  p.out = d_out; p.qsz = (long)B * K2F;

  char* w = (char*)d_ws;
  size_t used = 0;
  auto alloc = [&](size_t bytes) -> char* {
    char* r = w + used;
    used += (bytes + 255) & ~(size_t)255;
    return r;
  };
  p.flag  = (int*)alloc(4);
  p.segS  = (int*)alloc((size_t)B*4);
  p.segE  = (int*)alloc((size_t)B*4);
  p.embedB= (u16*)  alloc((size_t)p.embedN*2);
  p.W1eb  = (u16*)  alloc(16384*2);
  p.W2b   = (u16*)  alloc(16384*2);
  p.Wihb  = (u16*)  alloc(49152*2);
  p.Whhb  = (u16*)  alloc(49152*2);
  p.b1f   = (float*)alloc(NH*4);
  p.b2f   = (float*)alloc(NH*4);
  p.bihG  = (float*)alloc(NF*4);
  p.bhhG  = (float*)alloc(NF*4);
  p.WcatB = (u16*)  alloc((size_t)NG4*K2F*2);
  p.bsum  = (float*)alloc(NG4*4);
  p.h1v   = (float*)alloc(NF*4);
  p.c1v   = (float*)alloc(NF*4);
  p.hbuf  = (float*)alloc((size_t)B*NF*4);
  p.cbuf  = (float*)alloc((size_t)B*NF*4);
  p.xcatB = (u16*)  alloc((size_t)B*K2F*2);
  if (used > ws_size){
    (void)hipMemsetAsync(d_out, 0, (size_t)out_size * 2, stream);
    return;
  }
  // optional bf16 shadow of node_feature for attention reads (f32 mode only)
  const size_t nfbBytes = (size_t)N * NF * 2;
  if (used + nfbBytes + 256 <= ws_size){
    p.nfb = (u16*)alloc(nfbBytes);
    p.useNfb = 1;
  } else {
    p.nfb = (u16*)p.flag;   // unused; valid pointer
    p.useNfb = 0;
  }

  const long prepTot = (long)p.embedN + 16384 + 16384 + 49152 + 49152
                     + (long)NG4*K2F + NH + NH + NF + NF + NG4 + N;

  k_detect<<<1, 256, 0, stream>>>(p);
  k_prep  <<<(int)((prepTot + 255)/256), 256, 0, stream>>>(p);
  k_stageA_mfma<<<(N + 63)/64, 256, 0, stream>>>(p);
  k_lstm0 <<<1, NF, 0, stream>>>(p);

  const dim3 gemmG((B + 63)/64, NF/32);
  // Set2Set step 1 (q = broadcast h1); attn writes xcatB directly
  k_attn <<<B, 256, 0, stream>>>(p, p.h1v, 0, 0);
  k_gemm_fused<<<gemmG, 256, 0, stream>>>(p, p.c1v, 0);
  // step 2
  k_attn <<<B, 256, 0, stream>>>(p, p.hbuf, NF, 0);
  k_gemm_fused<<<gemmG, 256, 0, stream>>>(p, p.cbuf, NF);
  // step 3 (final: writes q_star)
  k_attn <<<B, 256, 0, stream>>>(p, p.hbuf, NF, 1);
}